// Round 1
// baseline (6741.185 us; speedup 1.0000x reference)
//
#include <hip/hip_runtime.h>
#include <math.h>

#define D 128
#define TOPK 3

// Kernel 1: per-target squared norms into workspace.
__global__ void tsq_kernel(const float* __restrict__ tgt, float* __restrict__ tsq, int M) {
    int j = blockIdx.x * blockDim.x + threadIdx.x;
    if (j >= M) return;
    const float4* t4 = reinterpret_cast<const float4*>(tgt + (size_t)j * D);
    float s0 = 0.f, s1 = 0.f, s2 = 0.f, s3 = 0.f;
#pragma unroll
    for (int k = 0; k < D / 4; ++k) {
        float4 v = t4[k];
        s0 = fmaf(v.x, v.x, s0);
        s1 = fmaf(v.y, v.y, s1);
        s2 = fmaf(v.z, v.z, s2);
        s3 = fmaf(v.w, v.w, s3);
    }
    tsq[j] = (s0 + s1) + (s2 + s3);
}

// Kernel 2: one thread per source row. Row lives in 32 x float4 registers.
// Inner loop over targets is wave-uniform -> target loads scalarize (SMEM/L2),
// VALU does 128 fp32 FMAs per target. Running top-3 (smallest shifted dist).
__global__ __launch_bounds__(64, 2)
void knn_topk_kernel(const float* __restrict__ src, const float* __restrict__ tgt,
                     const float* __restrict__ tsq, const float* __restrict__ tpts,
                     float* __restrict__ out, int N, int M) {
    int i = blockIdx.x * 64 + (int)threadIdx.x;
    int irow = i < N ? i : (N - 1);  // tail threads compute garbage, don't store

    float4 r[D / 4];
    const float4* s4 = reinterpret_cast<const float4*>(src + (size_t)irow * D);
#pragma unroll
    for (int k = 0; k < D / 4; ++k) r[k] = s4[k];

    float d0 = INFINITY, d1 = INFINITY, d2 = INFINITY;  // d0 <= d1 <= d2
    int i0 = 0, i1 = 0, i2 = 0;

    for (int j = 0; j < M; ++j) {
        const float4* t4 = reinterpret_cast<const float4*>(tgt + (size_t)j * D);
        float a0 = 0.f, a1 = 0.f, a2 = 0.f, a3 = 0.f;
#pragma unroll
        for (int k = 0; k < D / 4; ++k) {
            float4 t = t4[k];
            a0 = fmaf(r[k].x, t.x, a0);
            a1 = fmaf(r[k].y, t.y, a1);
            a2 = fmaf(r[k].z, t.z, a2);
            a3 = fmaf(r[k].w, t.w, a3);
        }
        float dp = (a0 + a1) + (a2 + a3);
        float c = fmaf(-2.f, dp, tsq[j]);  // shifted squared distance
        if (c < d2) {
            if (c < d1) {
                d2 = d1; i2 = i1;
                if (c < d0) { d1 = d0; i1 = i0; d0 = c; i0 = j; }
                else        { d1 = c;  i1 = j; }
            } else {
                d2 = c; i2 = j;
            }
        }
    }

    if (i >= N) return;

    // softmax over scores = -c (shift-invariant, source_sq dropped)
    float e0 = 1.f;                 // exp(-(d0-d0))
    float e1 = __expf(d0 - d1);
    float e2 = __expf(d0 - d2);
    float inv = 1.f / (e0 + e1 + e2);
    float w0 = e0 * inv, w1 = e1 * inv, w2 = e2 * inv;

    const float* p0 = tpts + 3 * (size_t)i0;
    const float* p1 = tpts + 3 * (size_t)i1;
    const float* p2 = tpts + 3 * (size_t)i2;
    float ox = w0 * p0[0] + w1 * p1[0] + w2 * p2[0];
    float oy = w0 * p0[1] + w1 * p1[1] + w2 * p2[1];
    float oz = w0 * p0[2] + w1 * p1[2] + w2 * p2[2];
    out[3 * (size_t)i + 0] = ox;
    out[3 * (size_t)i + 1] = oy;
    out[3 * (size_t)i + 2] = oz;
}

extern "C" void kernel_launch(void* const* d_in, const int* in_sizes, int n_in,
                              void* d_out, int out_size, void* d_ws, size_t ws_size,
                              hipStream_t stream) {
    const float* src  = (const float*)d_in[0];  // [N,128]
    const float* tgt  = (const float*)d_in[1];  // [M,128]
    const float* tpts = (const float*)d_in[2];  // [M,3]
    float* out = (float*)d_out;

    int N = in_sizes[0] / D;
    int M = in_sizes[1] / D;

    float* tsq = (float*)d_ws;  // M floats

    tsq_kernel<<<(M + 255) / 256, 256, 0, stream>>>(tgt, tsq, M);
    knn_topk_kernel<<<(N + 63) / 64, 64, 0, stream>>>(src, tgt, tsq, tpts, out, N, M);
}